// Round 6
// baseline (5164.142 us; speedup 1.0000x reference)
//
#include <hip/hip_runtime.h>
#include <hip/hip_bf16.h>

#define DM 200
#define DIE 400
#define LSEQ 256
#define NB 256

typedef __hip_bfloat16 bf16;
typedef const float* fp;

__device__ __forceinline__ float b2f(bf16 x) { return __bfloat162float(x); }
__device__ __forceinline__ bf16  f2b(float x) { return __float2bfloat16(x); }

__device__ __forceinline__ float ldf(const float* p) { return *p; }
__device__ __forceinline__ float ldf(const bf16* p) { return b2f(*p); }
__device__ __forceinline__ void stf(float* p, float v) { *p = v; }
__device__ __forceinline__ void stf(bf16* p, float v) { *p = f2b(v); }

// ---------------- generic NT GEMM: C[m,n] = sum_k A[m,k]*W[n,k] (+epilogue) ----------------
// EPI: 0=none, 2=gelu_exact(x+bias), 3=x+bias
template <typename TA, typename TC, int EPI>
__global__ __launch_bounds__(256) void gemm_nt(const TA* __restrict__ A, int lda,
                                               const float* __restrict__ W,
                                               const float* __restrict__ bias,
                                               TC* __restrict__ C, int ldc,
                                               int M, int N, int K) {
    __shared__ float As[16][65];
    __shared__ float Ws[16][65];
    const int m0 = blockIdx.x * 64;
    const int n0 = blockIdx.y * 64;
    const int tid = threadIdx.x;
    const int tx = tid & 15;   // n micro
    const int ty = tid >> 4;   // m micro
    float acc[4][4] = {};
    for (int k0 = 0; k0 < K; k0 += 16) {
#pragma unroll
        for (int i = 0; i < 4; ++i) {
            int idx = tid + i * 256;
            int m = idx >> 4, k = idx & 15;
            float v = 0.f;
            if (k0 + k < K) v = ldf(&A[(size_t)(m0 + m) * lda + k0 + k]);
            As[k][m] = v;
        }
#pragma unroll
        for (int i = 0; i < 4; ++i) {
            int idx = tid + i * 256;
            int n = idx >> 4, k = idx & 15;
            float v = 0.f;
            if ((n0 + n) < N && (k0 + k) < K) v = W[(size_t)(n0 + n) * K + k0 + k];
            Ws[k][n] = v;
        }
        __syncthreads();
#pragma unroll
        for (int k = 0; k < 16; ++k) {
            float a[4], w[4];
#pragma unroll
            for (int i = 0; i < 4; ++i) a[i] = As[k][ty * 4 + i];
#pragma unroll
            for (int j = 0; j < 4; ++j) w[j] = Ws[k][tx * 4 + j];
#pragma unroll
            for (int i = 0; i < 4; ++i)
#pragma unroll
                for (int j = 0; j < 4; ++j) acc[i][j] += a[i] * w[j];
        }
        __syncthreads();
    }
#pragma unroll
    for (int i = 0; i < 4; ++i) {
        int m = m0 + ty * 4 + i;
#pragma unroll
        for (int j = 0; j < 4; ++j) {
            int n = n0 + tx * 4 + j;
            if (n < N && m < M) {
                float v = acc[i][j];
                if (EPI == 2) {
                    v += bias[n];
                    v = 0.5f * v * (1.f + erff(v * 0.70710678118654752f));
                } else if (EPI == 3) {
                    v += bias[n];
                }
                stf(&C[(size_t)m * ldc + n], v);
            }
        }
    }
}

// ---------------- causal depthwise conv (k=4) + bias + silu, IN-PLACE on x-half ----------------
__global__ __launch_bounds__(256) void conv_silu_inplace(bf16* __restrict__ xz,
                                                         const float* __restrict__ cw,
                                                         const float* __restrict__ cb,
                                                         int total /* chunkB*DIE */) {
    int idx = blockIdx.x * 256 + threadIdx.x;
    if (idx >= total) return;
    int d = idx % DIE;
    int b = idx / DIE;   // chunk-local
    float w0 = cw[d * 4 + 0];
    float w1 = cw[d * 4 + 1];
    float w2 = cw[d * 4 + 2];
    float w3 = cw[d * 4 + 3];
    float bias = cb[d];
    float x0 = 0.f, x1 = 0.f, x2 = 0.f;
    bf16* p = xz + (size_t)b * LSEQ * 800 + d;
    for (int t = 0; t < LSEQ; ++t) {
        float x = b2f(*p);
        float s = bias + w0 * x0 + w1 * x1 + w2 * x2 + w3 * x;
        x0 = x1; x1 = x2; x2 = x;
        float sig = 1.f / (1.f + expf(-s));
        *p = f2b(s * sig);
        p += 800;
    }
}

// ---------------- fused selective scan (delta GEMV + recurrence + D-skip + silu(z) gate) ----
// grid: chunkB*2 blocks, 256 threads; block covers 200 channels. y in-place over x-half.
__global__ __launch_bounds__(256) void scan_kernel(const float* __restrict__ xdbl,
                                                   bf16* __restrict__ xz,
                                                   const float* __restrict__ dt_w,
                                                   const float* __restrict__ dt_b,
                                                   const float* __restrict__ A_log,
                                                   const float* __restrict__ Dw) {
    int b = blockIdx.x >> 1;        // chunk-local
    int half = blockIdx.x & 1;
    int tid = threadIdx.x;
    int d = half * 200 + tid;
    bool active = tid < 200;
    __shared__ float srow[45];
    float A[16], Wr[13];
    float bdt = 0.f, Dv = 0.f;
    if (active) {
#pragma unroll
        for (int n = 0; n < 16; ++n) A[n] = -expf(A_log[d * 16 + n]);
#pragma unroll
        for (int r = 0; r < 13; ++r) Wr[r] = dt_w[d * 13 + r];
        bdt = dt_b[d];
        Dv = Dw[d];
    }
    float h[16];
#pragma unroll
    for (int n = 0; n < 16; ++n) h[n] = 0.f;
    size_t base = (size_t)b * LSEQ;
    for (int t = 0; t < LSEQ; ++t) {
        size_t row = base + t;
        if (tid < 45) srow[tid] = xdbl[row * 45 + tid];
        __syncthreads();
        if (active) {
            float dtv = bdt;
#pragma unroll
            for (int r = 0; r < 13; ++r) dtv += Wr[r] * srow[r];
            dtv = (dtv > 20.f) ? dtv : log1pf(expf(dtv));
            size_t xoff = row * 800 + d;
            float ut = b2f(xz[xoff]);
            float zv = b2f(xz[xoff + 400]);
            float du = dtv * ut;
            float yv = 0.f;
#pragma unroll
            for (int n = 0; n < 16; ++n) {
                float dA = expf(dtv * A[n]);
                h[n] = dA * h[n] + du * srow[13 + n];
                yv += h[n] * srow[29 + n];
            }
            yv += ut * Dv;
            float sig = 1.f / (1.f + expf(-zv));
            xz[xoff] = f2b(yv * zv * sig);
        }
        __syncthreads();
    }
}

// ---------------- residual + layernorm over 200: dst = ln(xa+xb)*w + b ----------------
__global__ __launch_bounds__(256) void ln_res_kernel(const float* __restrict__ xa,
                                                     const float* __restrict__ xb,
                                                     const float* __restrict__ w,
                                                     const float* __restrict__ bias,
                                                     float* __restrict__ dst, int rows) {
    int wave = threadIdx.x >> 6;
    int lane = threadIdx.x & 63;
    int row = blockIdx.x * 4 + wave;
    if (row >= rows) return;
    const float* pa = xa + (size_t)row * DM;
    const float* pb = xb + (size_t)row * DM;
    float v[4];
    float sum = 0.f, sq = 0.f;
#pragma unroll
    for (int i = 0; i < 4; ++i) {
        int c = lane + i * 64;
        float t = 0.f;
        if (c < DM) t = pa[c] + pb[c];
        v[i] = t;
        sum += t;
        sq += t * t;
    }
#pragma unroll
    for (int off = 32; off > 0; off >>= 1) {
        sum += __shfl_down(sum, off);
        sq += __shfl_down(sq, off);
    }
    sum = __shfl(sum, 0);
    sq = __shfl(sq, 0);
    float mu = sum * (1.f / DM);
    float var = fmaxf(sq * (1.f / DM) - mu * mu, 0.f);
    float rstd = rsqrtf(var + 1e-12f);
    float* pd = dst + (size_t)row * DM;
#pragma unroll
    for (int i = 0; i < 4; ++i) {
        int c = lane + i * 64;
        if (c < DM) pd[c] = (v[i] - mu) * rstd * w[c] + bias[c];
    }
}

// ---------------- output split for a batch chunk (f32 out) ----------------
__global__ __launch_bounds__(256) void write_out_kernel(const float* __restrict__ h,
                                                        float* __restrict__ out,
                                                        int b0, int total /* rc*DM */) {
    int idx = blockIdx.x * 256 + threadIdx.x;
    if (idx >= total) return;
    int d = idx % DM;
    int bl = idx / DM;
    int l = bl % LSEQ;
    int b = b0 + bl / LSEQ;   // global batch
    float v = h[idx];
    if (l == LSEQ - 1) {
        out[b * DM + d] = v;
    } else {
        out[(size_t)NB * DM + ((size_t)(b * (LSEQ - 1) + l) * DM + d)] = v;
    }
}

extern "C" void kernel_launch(void* const* d_in, const int* in_sizes, int n_in,
                              void* d_out, int out_size, void* d_ws, size_t ws_size,
                              hipStream_t stream) {
    fp emb       = (fp)d_in[0];
    // d_in[1] item_seq_len (int32): unused by reference
    fp in_proj_w = (fp)d_in[2];
    fp conv_w    = (fp)d_in[3];
    fp conv_b    = (fp)d_in[4];
    fp x_proj_w  = (fp)d_in[5];
    fp dt_proj_w = (fp)d_in[6];
    fp dt_proj_b = (fp)d_in[7];
    fp A_log     = (fp)d_in[8];
    fp Dw        = (fp)d_in[9];
    fp out_proj_w= (fp)d_in[10];
    fp ln1_w     = (fp)d_in[11];
    fp ln1_b     = (fp)d_in[12];
    fp ffn_w1    = (fp)d_in[13];
    fp ffn_b1    = (fp)d_in[14];
    fp ffn_w2    = (fp)d_in[15];
    fp ffn_b2    = (fp)d_in[16];
    fp ffn_ln_w  = (fp)d_in[17];
    fp ffn_ln_b  = (fp)d_in[18];

    // Pick the largest batch-chunk whose scratch fits ws_size.
    // per-chunk bytes/row: xz (800 bf16 = 1600) + xdbl (45 f32 = 180) + m (200 f32 = 800)
    //                      + h (200 f32 = 800) = 3380; rows per chunk rc = cb*256
    const int cands[8] = {256, 128, 64, 32, 16, 8, 4, 2};
    int cb = 2;
    for (int ci = 0; ci < 8; ++ci) {
        size_t rcx = (size_t)cands[ci] * LSEQ;
        if (rcx * 3380 <= ws_size) { cb = cands[ci]; break; }
    }
    const size_t rc = (size_t)cb * LSEQ;   // rows per chunk

    bf16*  xz   = (bf16*)d_ws;                 // rc*800
    float* xdbl = (float*)(xz + rc * 800);     // rc*45
    float* m    = xdbl + rc * 45;              // rc*200
    float* h    = m + rc * 200;                // rc*200

    const int rcDM = (int)rc * DM;

    for (int b0 = 0; b0 < NB; b0 += cb) {
        const float* emb_chunk = emb + (size_t)b0 * LSEQ * DM;

        for (int i = 0; i < 2; ++i) {
            fp w_in  = in_proj_w + (size_t)i * 800 * 200;
            fp cw    = conv_w + (size_t)i * 400 * 4;
            fp cbp   = conv_b + (size_t)i * 400;
            fp w_xp  = x_proj_w + (size_t)i * 45 * 400;
            fp w_dt  = dt_proj_w + (size_t)i * 400 * 13;
            fp b_dt  = dt_proj_b + (size_t)i * 400;
            fp Ai    = A_log + (size_t)i * 400 * 16;
            fp Di    = Dw + (size_t)i * 400;
            fp w_op  = out_proj_w + (size_t)i * 200 * 400;
            fp l1w   = ln1_w + (size_t)i * 200;
            fp l1b   = ln1_b + (size_t)i * 200;
            fp f1w   = ffn_w1 + (size_t)i * 800 * 200;
            fp f1b   = ffn_b1 + (size_t)i * 800;
            fp f2w   = ffn_w2 + (size_t)i * 200 * 800;
            fp f2b_  = ffn_b2 + (size_t)i * 200;
            fp flw   = ffn_ln_w + (size_t)i * 200;
            fp flb   = ffn_ln_b + (size_t)i * 200;

            // layer 0 reads the residual stream straight from item_emb
            const float* hin = (i == 0) ? emb_chunk : h;

            // xz = hin @ in_proj^T   (M=rc, N=800, K=200)
            gemm_nt<float, bf16, 0><<<dim3(rc / 64, 13), 256, 0, stream>>>(
                hin, 200, w_in, nullptr, xz, 800, (int)rc, 800, 200);
            // conv + silu in-place on x-half
            conv_silu_inplace<<<(cb * DIE + 255) / 256, 256, 0, stream>>>(xz, cw, cbp, cb * DIE);
            // xdbl = xc @ x_proj^T   (N=45, K=400)
            gemm_nt<bf16, float, 0><<<dim3(rc / 64, 1), 256, 0, stream>>>(
                xz, 800, w_xp, nullptr, xdbl, 45, (int)rc, 45, 400);
            // fused scan; y in-place on x-half
            scan_kernel<<<cb * 2, 256, 0, stream>>>(xdbl, xz, w_dt, b_dt, Ai, Di);
            // m = y @ out_proj^T   (N=200, K=400)
            gemm_nt<bf16, float, 0><<<dim3(rc / 64, 4), 256, 0, stream>>>(
                xz, 800, w_op, nullptr, m, 200, (int)rc, 200, 400);
            // h = ln(m + hin)
            ln_res_kernel<<<rc / 4, 256, 0, stream>>>(m, hin, l1w, l1b, h, (int)rc);
            // f1 = gelu(h @ w1^T + b1) -> xz
            gemm_nt<float, bf16, 2><<<dim3(rc / 64, 13), 256, 0, stream>>>(
                h, 200, f1w, f1b, xz, 800, (int)rc, 800, 200);
            // f2 = f1 @ w2^T + b2 -> m   (N=200, K=800)
            gemm_nt<bf16, float, 3><<<dim3(rc / 64, 4), 256, 0, stream>>>(
                xz, 800, f2w, f2b_, m, 200, (int)rc, 200, 800);
            // h = ln(f2 + h)
            ln_res_kernel<<<rc / 4, 256, 0, stream>>>(m, h, flw, flb, h, (int)rc);
        }

        write_out_kernel<<<rcDM / 256, 256, 0, stream>>>(h, (float*)d_out, b0, rcDM);
    }
}

// Round 7
// 2119.658 us; speedup vs baseline: 2.4363x; 2.4363x over previous
//
#include <hip/hip_runtime.h>
#include <hip/hip_bf16.h>

#define DM 200
#define DIE 400
#define LSEQ 256
#define NB 256

typedef __hip_bfloat16 bf16;
typedef const float* fp;
typedef __attribute__((ext_vector_type(8))) short short8;
typedef __attribute__((ext_vector_type(4))) float f32x4;

__device__ __forceinline__ float b2f(bf16 x) { return __bfloat162float(x); }
__device__ __forceinline__ bf16  f2b(float x) { return __float2bfloat16(x); }

// f32 -> bf16 bits (round-to-nearest-even)
__device__ __forceinline__ unsigned short f2bbits(float f) {
    union { float f; unsigned int u; } c; c.f = f;
    unsigned int u = c.u;
    unsigned int r = (u + 0x7fffu + ((u >> 16) & 1u)) >> 16;
    return (unsigned short)r;
}
__device__ __forceinline__ unsigned short ldb(const float* p) { return f2bbits(*p); }
__device__ __forceinline__ unsigned short ldb(const bf16* p) { return *(const unsigned short*)p; }
__device__ __forceinline__ void stf(float* p, float v) { *p = v; }
__device__ __forceinline__ void stf(bf16* p, float v) { *p = f2b(v); }

// ---------------- MFMA NT GEMM: C[m,n] = sum_k A[m,k]*W[n,k] (+epilogue) ----------------
// Block tile 128(m) x 128(n), K-step 32, 4 waves in 2x2; wave subtile 64x64 = 4x4 MFMA tiles.
// M must be a multiple of 128 (guaranteed: M = cb*256). N,K arbitrary (masked).
// EPI: 0=none, 2=gelu_exact(x+bias), 3=x+bias
template <typename TA, typename TC, int EPI>
__global__ __launch_bounds__(256) void gemm_mfma(const TA* __restrict__ A, int lda,
                                                 const float* __restrict__ W,
                                                 const float* __restrict__ bias,
                                                 TC* __restrict__ C, int ldc,
                                                 int N, int K) {
    constexpr int LS = 40;                       // LDS row stride in shorts (32 + 8 pad, 80 B)
    __shared__ short As[128 * LS];
    __shared__ short Bs[128 * LS];
    const int m0 = blockIdx.x * 128;
    const int n0 = blockIdx.y * 128;
    const int tid = threadIdx.x;
    const int wave = tid >> 6;
    const int lane = tid & 63;
    const int wm = (wave & 1) * 64;
    const int wn = (wave >> 1) * 64;
    const int fm = lane & 15;
    const int quad = lane >> 4;

    f32x4 acc[4][4] = {};

    const int sr = tid >> 1;                     // staging row 0..127
    const int sc = (tid & 1) * 16;               // staging col 0 / 16

    for (int k0 = 0; k0 < K; k0 += 32) {
        // stage A: 128x32 (16 elems/thread)
        {
            const TA* src = A + (size_t)(m0 + sr) * lda + k0 + sc;
            short* dst = As + sr * LS + sc;
            if (k0 + sc + 16 <= K) {
#pragma unroll
                for (int j = 0; j < 16; ++j) dst[j] = (short)ldb(src + j);
            } else {
#pragma unroll
                for (int j = 0; j < 16; ++j)
                    dst[j] = (k0 + sc + j < K) ? (short)ldb(src + j) : (short)0;
            }
        }
        // stage B(W): 128x32 (16 elems/thread), mask n and k
        {
            short* dst = Bs + sr * LS + sc;
            if (n0 + sr < N) {
                const float* src = W + (size_t)(n0 + sr) * K + k0 + sc;
                if (k0 + sc + 16 <= K) {
#pragma unroll
                    for (int j = 0; j < 16; ++j) dst[j] = (short)f2bbits(src[j]);
                } else {
#pragma unroll
                    for (int j = 0; j < 16; ++j)
                        dst[j] = (k0 + sc + j < K) ? (short)f2bbits(src[j]) : (short)0;
                }
            } else {
#pragma unroll
                for (int j = 0; j < 16; ++j) dst[j] = 0;
            }
        }
        __syncthreads();
        // fragments: A[m=lane&15][k=quad*8+j], B[n=lane&15][k=quad*8+j]
        short8 af[4], bfr[4];
#pragma unroll
        for (int i = 0; i < 4; ++i)
            af[i] = *(const short8*)(As + (wm + i * 16 + fm) * LS + quad * 8);
#pragma unroll
        for (int j = 0; j < 4; ++j)
            bfr[j] = *(const short8*)(Bs + (wn + j * 16 + fm) * LS + quad * 8);
#pragma unroll
        for (int i = 0; i < 4; ++i)
#pragma unroll
            for (int j = 0; j < 4; ++j)
                acc[i][j] = __builtin_amdgcn_mfma_f32_16x16x32_bf16(af[i], bfr[j], acc[i][j], 0, 0, 0);
        __syncthreads();
    }

    // epilogue: D[m = quad*4 + r][n = fm] per 16x16 tile
#pragma unroll
    for (int j = 0; j < 4; ++j) {
        int n = n0 + wn + j * 16 + fm;
        if (n >= N) continue;
        float bv = (EPI == 2 || EPI == 3) ? bias[n] : 0.f;
#pragma unroll
        for (int i = 0; i < 4; ++i) {
#pragma unroll
            for (int r = 0; r < 4; ++r) {
                int m = m0 + wm + i * 16 + quad * 4 + r;
                float v = acc[i][j][r];
                if (EPI == 2) {
                    v += bv;
                    v = 0.5f * v * (1.f + erff(v * 0.70710678118654752f));
                } else if (EPI == 3) {
                    v += bv;
                }
                stf(&C[(size_t)m * ldc + n], v);
            }
        }
    }
}

// ---------------- causal depthwise conv (k=4) + bias + silu, IN-PLACE on x-half ----------------
__global__ __launch_bounds__(256) void conv_silu_inplace(bf16* __restrict__ xz,
                                                         const float* __restrict__ cw,
                                                         const float* __restrict__ cb,
                                                         int total /* chunkB*DIE */) {
    int idx = blockIdx.x * 256 + threadIdx.x;
    if (idx >= total) return;
    int d = idx % DIE;
    int b = idx / DIE;
    float w0 = cw[d * 4 + 0];
    float w1 = cw[d * 4 + 1];
    float w2 = cw[d * 4 + 2];
    float w3 = cw[d * 4 + 3];
    float bias = cb[d];
    float x0 = 0.f, x1 = 0.f, x2 = 0.f;
    bf16* p = xz + (size_t)b * LSEQ * 800 + d;
    for (int t = 0; t < LSEQ; ++t) {
        float x = b2f(*p);
        float s = bias + w0 * x0 + w1 * x1 + w2 * x2 + w3 * x;
        x0 = x1; x1 = x2; x2 = x;
        float sig = 1.f / (1.f + expf(-s));
        *p = f2b(s * sig);
        p += 800;
    }
}

// ---------------- fused selective scan ----------------
__global__ __launch_bounds__(256) void scan_kernel(const float* __restrict__ xdbl,
                                                   bf16* __restrict__ xz,
                                                   const float* __restrict__ dt_w,
                                                   const float* __restrict__ dt_b,
                                                   const float* __restrict__ A_log,
                                                   const float* __restrict__ Dw) {
    int b = blockIdx.x >> 1;
    int half = blockIdx.x & 1;
    int tid = threadIdx.x;
    int d = half * 200 + tid;
    bool active = tid < 200;
    __shared__ float srow[45];
    float A[16], Wr[13];
    float bdt = 0.f, Dv = 0.f;
    if (active) {
#pragma unroll
        for (int n = 0; n < 16; ++n) A[n] = -expf(A_log[d * 16 + n]);
#pragma unroll
        for (int r = 0; r < 13; ++r) Wr[r] = dt_w[d * 13 + r];
        bdt = dt_b[d];
        Dv = Dw[d];
    }
    float h[16];
#pragma unroll
    for (int n = 0; n < 16; ++n) h[n] = 0.f;
    size_t base = (size_t)b * LSEQ;
    for (int t = 0; t < LSEQ; ++t) {
        size_t row = base + t;
        if (tid < 45) srow[tid] = xdbl[row * 45 + tid];
        __syncthreads();
        if (active) {
            float dtv = bdt;
#pragma unroll
            for (int r = 0; r < 13; ++r) dtv += Wr[r] * srow[r];
            dtv = (dtv > 20.f) ? dtv : log1pf(expf(dtv));
            size_t xoff = row * 800 + d;
            float ut = b2f(xz[xoff]);
            float zv = b2f(xz[xoff + 400]);
            float du = dtv * ut;
            float yv = 0.f;
#pragma unroll
            for (int n = 0; n < 16; ++n) {
                float dA = expf(dtv * A[n]);
                h[n] = dA * h[n] + du * srow[13 + n];
                yv += h[n] * srow[29 + n];
            }
            yv += ut * Dv;
            float sig = 1.f / (1.f + expf(-zv));
            xz[xoff] = f2b(yv * zv * sig);
        }
        __syncthreads();
    }
}

// ---------------- residual + layernorm over 200 ----------------
__global__ __launch_bounds__(256) void ln_res_kernel(const float* __restrict__ xa,
                                                     const float* __restrict__ xb,
                                                     const float* __restrict__ w,
                                                     const float* __restrict__ bias,
                                                     float* __restrict__ dst, int rows) {
    int wave = threadIdx.x >> 6;
    int lane = threadIdx.x & 63;
    int row = blockIdx.x * 4 + wave;
    if (row >= rows) return;
    const float* pa = xa + (size_t)row * DM;
    const float* pb = xb + (size_t)row * DM;
    float v[4];
    float sum = 0.f, sq = 0.f;
#pragma unroll
    for (int i = 0; i < 4; ++i) {
        int c = lane + i * 64;
        float t = 0.f;
        if (c < DM) t = pa[c] + pb[c];
        v[i] = t;
        sum += t;
        sq += t * t;
    }
#pragma unroll
    for (int off = 32; off > 0; off >>= 1) {
        sum += __shfl_down(sum, off);
        sq += __shfl_down(sq, off);
    }
    sum = __shfl(sum, 0);
    sq = __shfl(sq, 0);
    float mu = sum * (1.f / DM);
    float var = fmaxf(sq * (1.f / DM) - mu * mu, 0.f);
    float rstd = rsqrtf(var + 1e-12f);
    float* pd = dst + (size_t)row * DM;
#pragma unroll
    for (int i = 0; i < 4; ++i) {
        int c = lane + i * 64;
        if (c < DM) pd[c] = (v[i] - mu) * rstd * w[c] + bias[c];
    }
}

// ---------------- output split for a batch chunk (f32 out) ----------------
__global__ __launch_bounds__(256) void write_out_kernel(const float* __restrict__ h,
                                                        float* __restrict__ out,
                                                        int b0, int total /* rc*DM */) {
    int idx = blockIdx.x * 256 + threadIdx.x;
    if (idx >= total) return;
    int d = idx % DM;
    int bl = idx / DM;
    int l = bl % LSEQ;
    int b = b0 + bl / LSEQ;
    float v = h[idx];
    if (l == LSEQ - 1) {
        out[b * DM + d] = v;
    } else {
        out[(size_t)NB * DM + ((size_t)(b * (LSEQ - 1) + l) * DM + d)] = v;
    }
}

extern "C" void kernel_launch(void* const* d_in, const int* in_sizes, int n_in,
                              void* d_out, int out_size, void* d_ws, size_t ws_size,
                              hipStream_t stream) {
    fp emb       = (fp)d_in[0];
    fp in_proj_w = (fp)d_in[2];
    fp conv_w    = (fp)d_in[3];
    fp conv_b    = (fp)d_in[4];
    fp x_proj_w  = (fp)d_in[5];
    fp dt_proj_w = (fp)d_in[6];
    fp dt_proj_b = (fp)d_in[7];
    fp A_log     = (fp)d_in[8];
    fp Dw        = (fp)d_in[9];
    fp out_proj_w= (fp)d_in[10];
    fp ln1_w     = (fp)d_in[11];
    fp ln1_b     = (fp)d_in[12];
    fp ffn_w1    = (fp)d_in[13];
    fp ffn_b1    = (fp)d_in[14];
    fp ffn_w2    = (fp)d_in[15];
    fp ffn_b2    = (fp)d_in[16];
    fp ffn_ln_w  = (fp)d_in[17];
    fp ffn_ln_b  = (fp)d_in[18];

    // per-chunk bytes/row: xz 1600 + xdbl 180 + m 800 + h 800 = 3380; rc = cb*256
    const int cands[8] = {256, 128, 64, 32, 16, 8, 4, 2};
    int cb = 2;
    for (int ci = 0; ci < 8; ++ci) {
        size_t rcx = (size_t)cands[ci] * LSEQ;
        if (rcx * 3380 <= ws_size) { cb = cands[ci]; break; }
    }
    const size_t rc = (size_t)cb * LSEQ;

    bf16*  xz   = (bf16*)d_ws;                 // rc*800
    float* xdbl = (float*)(xz + rc * 800);     // rc*45
    float* m    = xdbl + rc * 45;              // rc*200
    float* h    = m + rc * 200;                // rc*200

    const int rcDM = (int)rc * DM;
    const int gm = (int)rc / 128;              // m-tiles

    for (int b0 = 0; b0 < NB; b0 += cb) {
        const float* emb_chunk = emb + (size_t)b0 * LSEQ * DM;

        for (int i = 0; i < 2; ++i) {
            fp w_in  = in_proj_w + (size_t)i * 800 * 200;
            fp cw    = conv_w + (size_t)i * 400 * 4;
            fp cbp   = conv_b + (size_t)i * 400;
            fp w_xp  = x_proj_w + (size_t)i * 45 * 400;
            fp w_dt  = dt_proj_w + (size_t)i * 400 * 13;
            fp b_dt  = dt_proj_b + (size_t)i * 400;
            fp Ai    = A_log + (size_t)i * 400 * 16;
            fp Di    = Dw + (size_t)i * 400;
            fp w_op  = out_proj_w + (size_t)i * 200 * 400;
            fp l1w   = ln1_w + (size_t)i * 200;
            fp l1b   = ln1_b + (size_t)i * 200;
            fp f1w   = ffn_w1 + (size_t)i * 800 * 200;
            fp f1b   = ffn_b1 + (size_t)i * 800;
            fp f2w   = ffn_w2 + (size_t)i * 200 * 800;
            fp f2b_  = ffn_b2 + (size_t)i * 200;
            fp flw   = ffn_ln_w + (size_t)i * 200;
            fp flb   = ffn_ln_b + (size_t)i * 200;

            const float* hin = (i == 0) ? emb_chunk : h;

            // xz = hin @ in_proj^T   (N=800, K=200)
            gemm_mfma<float, bf16, 0><<<dim3(gm, 7), 256, 0, stream>>>(
                hin, 200, w_in, nullptr, xz, 800, 800, 200);
            // conv + silu in-place on x-half
            conv_silu_inplace<<<(cb * DIE + 255) / 256, 256, 0, stream>>>(xz, cw, cbp, cb * DIE);
            // xdbl = xc @ x_proj^T   (N=45, K=400)
            gemm_mfma<bf16, float, 0><<<dim3(gm, 1), 256, 0, stream>>>(
                xz, 800, w_xp, nullptr, xdbl, 45, 45, 400);
            // fused scan; y in-place on x-half
            scan_kernel<<<cb * 2, 256, 0, stream>>>(xdbl, xz, w_dt, b_dt, Ai, Di);
            // m = y @ out_proj^T   (N=200, K=400)
            gemm_mfma<bf16, float, 0><<<dim3(gm, 2), 256, 0, stream>>>(
                xz, 800, w_op, nullptr, m, 200, 200, 400);
            // h = ln(m + hin)
            ln_res_kernel<<<rc / 4, 256, 0, stream>>>(m, hin, l1w, l1b, h, (int)rc);
            // f1 = gelu(h @ w1^T + b1) -> xz
            gemm_mfma<float, bf16, 2><<<dim3(gm, 7), 256, 0, stream>>>(
                h, 200, f1w, f1b, xz, 800, 800, 200);
            // f2 = f1 @ w2^T + b2 -> m   (N=200, K=800)
            gemm_mfma<bf16, float, 3><<<dim3(gm, 2), 256, 0, stream>>>(
                xz, 800, f2w, f2b_, m, 200, 200, 800);
            // h = ln(f2 + h)
            ln_res_kernel<<<rc / 4, 256, 0, stream>>>(m, h, flw, flb, h, (int)rc);
        }

        write_out_kernel<<<rcDM / 256, 256, 0, stream>>>(h, (float*)d_out, b0, rcDM);
    }
}

// Round 8
// 2028.164 us; speedup vs baseline: 2.5462x; 1.0451x over previous
//
#include <hip/hip_runtime.h>
#include <hip/hip_bf16.h>

#define DM 200
#define DIE 400
#define LSEQ 256
#define NB 256

typedef __hip_bfloat16 bf16;
typedef const float* fp;
typedef __attribute__((ext_vector_type(8))) short short8;
typedef __attribute__((ext_vector_type(4))) float f32x4;

__device__ __forceinline__ float b2f(bf16 x) { return __bfloat162float(x); }
__device__ __forceinline__ bf16  f2b(float x) { return __float2bfloat16(x); }

// f32 -> bf16 bits (round-to-nearest-even)
__device__ __forceinline__ unsigned short f2bbits(float f) {
    union { float f; unsigned int u; } c; c.f = f;
    unsigned int u = c.u;
    unsigned int r = (u + 0x7fffu + ((u >> 16) & 1u)) >> 16;
    return (unsigned short)r;
}
__device__ __forceinline__ unsigned short ldb(const float* p) { return f2bbits(*p); }
__device__ __forceinline__ unsigned short ldb(const bf16* p) { return *(const unsigned short*)p; }
__device__ __forceinline__ void stf(float* p, float v) { *p = v; }
__device__ __forceinline__ void stf(bf16* p, float v) { *p = f2b(v); }

// ---------------- MFMA NT GEMM: C[m,n] = sum_k A[m,k]*W[n,k] (+epilogue) ----------------
// Block tile 128(m) x 128(n), K-step 32, 4 waves in 2x2; wave subtile 64x64 = 4x4 MFMA tiles.
// EPI: 0=none, 2=gelu_exact(x+bias), 3=x+bias
template <typename TA, typename TC, int EPI>
__global__ __launch_bounds__(256) void gemm_mfma(const TA* __restrict__ A, int lda,
                                                 const float* __restrict__ W,
                                                 const float* __restrict__ bias,
                                                 TC* __restrict__ C, int ldc,
                                                 int N, int K) {
    constexpr int LS = 40;                       // LDS row stride in shorts (32 + 8 pad, 80 B)
    __shared__ short As[128 * LS];
    __shared__ short Bs[128 * LS];
    const int m0 = blockIdx.x * 128;
    const int n0 = blockIdx.y * 128;
    const int tid = threadIdx.x;
    const int wave = tid >> 6;
    const int lane = tid & 63;
    const int wm = (wave & 1) * 64;
    const int wn = (wave >> 1) * 64;
    const int fm = lane & 15;
    const int quad = lane >> 4;

    f32x4 acc[4][4] = {};

    const int sr = tid >> 1;                     // staging row 0..127
    const int sc = (tid & 1) * 16;               // staging col 0 / 16

    for (int k0 = 0; k0 < K; k0 += 32) {
        // stage A: 128x32 (16 elems/thread)
        {
            const TA* src = A + (size_t)(m0 + sr) * lda + k0 + sc;
            short* dst = As + sr * LS + sc;
            if (k0 + sc + 16 <= K) {
#pragma unroll
                for (int j = 0; j < 16; ++j) dst[j] = (short)ldb(src + j);
            } else {
#pragma unroll
                for (int j = 0; j < 16; ++j)
                    dst[j] = (k0 + sc + j < K) ? (short)ldb(src + j) : (short)0;
            }
        }
        // stage B(W): 128x32 (16 elems/thread), mask n and k
        {
            short* dst = Bs + sr * LS + sc;
            if (n0 + sr < N) {
                const float* src = W + (size_t)(n0 + sr) * K + k0 + sc;
                if (k0 + sc + 16 <= K) {
#pragma unroll
                    for (int j = 0; j < 16; ++j) dst[j] = (short)f2bbits(src[j]);
                } else {
#pragma unroll
                    for (int j = 0; j < 16; ++j)
                        dst[j] = (k0 + sc + j < K) ? (short)f2bbits(src[j]) : (short)0;
                }
            } else {
#pragma unroll
                for (int j = 0; j < 16; ++j) dst[j] = 0;
            }
        }
        __syncthreads();
        short8 af[4], bfr[4];
#pragma unroll
        for (int i = 0; i < 4; ++i)
            af[i] = *(const short8*)(As + (wm + i * 16 + fm) * LS + quad * 8);
#pragma unroll
        for (int j = 0; j < 4; ++j)
            bfr[j] = *(const short8*)(Bs + (wn + j * 16 + fm) * LS + quad * 8);
#pragma unroll
        for (int i = 0; i < 4; ++i)
#pragma unroll
            for (int j = 0; j < 4; ++j)
                acc[i][j] = __builtin_amdgcn_mfma_f32_16x16x32_bf16(af[i], bfr[j], acc[i][j], 0, 0, 0);
        __syncthreads();
    }

    // epilogue: D[m = quad*4 + r][n = fm] per 16x16 tile
#pragma unroll
    for (int j = 0; j < 4; ++j) {
        int n = n0 + wn + j * 16 + fm;
        if (n >= N) continue;
        float bv = (EPI == 2 || EPI == 3) ? bias[n] : 0.f;
#pragma unroll
        for (int i = 0; i < 4; ++i) {
#pragma unroll
            for (int r = 0; r < 4; ++r) {
                int m = m0 + wm + i * 16 + quad * 4 + r;
                float v = acc[i][j][r];
                if (EPI == 2) {
                    v += bv;
                    v = 0.5f * v * (1.f + erff(v * 0.70710678118654752f));
                } else if (EPI == 3) {
                    v += bv;
                }
                stf(&C[(size_t)m * ldc + n], v);
            }
        }
    }
}

// ---------------- causal depthwise conv (k=4) + bias + silu, IN-PLACE on x-half ----------------
__global__ __launch_bounds__(256) void conv_silu_inplace(bf16* __restrict__ xz,
                                                         const float* __restrict__ cw,
                                                         const float* __restrict__ cb,
                                                         int total /* chunkB*DIE */) {
    int idx = blockIdx.x * 256 + threadIdx.x;
    if (idx >= total) return;
    int d = idx % DIE;
    int b = idx / DIE;
    float w0 = cw[d * 4 + 0];
    float w1 = cw[d * 4 + 1];
    float w2 = cw[d * 4 + 2];
    float w3 = cw[d * 4 + 3];
    float bias = cb[d];
    float x0 = 0.f, x1 = 0.f, x2 = 0.f;
    bf16* p = xz + (size_t)b * LSEQ * 800 + d;
    for (int t = 0; t < LSEQ; ++t) {
        float x = b2f(*p);
        float s = bias + w0 * x0 + w1 * x1 + w2 * x2 + w3 * x;
        x0 = x1; x1 = x2; x2 = x;
        float sig = 1.f / (1.f + expf(-s));
        *p = f2b(s * sig);
        p += 800;
    }
}

// ---------------- fused selective scan, barrier-free + software-pipelined ----------------
// grid: chunkB*2 blocks, 256 threads (200 active); per-lane channel d, h[16] in regs.
// srow address is wave-uniform -> scalar/broadcast loads; t+1 prefetched during t compute.
__global__ __launch_bounds__(256) void scan_kernel(const float* __restrict__ xdbl,
                                                   bf16* __restrict__ xz,
                                                   const float* __restrict__ dt_w,
                                                   const float* __restrict__ dt_b,
                                                   const float* __restrict__ A_log,
                                                   const float* __restrict__ Dw) {
    const int b = blockIdx.x >> 1;
    const int half = blockIdx.x & 1;
    const int tid = threadIdx.x;
    if (tid >= 200) return;            // no barriers below -> legal early exit
    const int d = half * 200 + tid;

    float A[16], Wr[13];
#pragma unroll
    for (int n = 0; n < 16; ++n) A[n] = -expf(A_log[d * 16 + n]);
#pragma unroll
    for (int r = 0; r < 13; ++r) Wr[r] = dt_w[d * 13 + r];
    const float bdt = dt_b[d];
    const float Dv = Dw[d];

    float h[16];
#pragma unroll
    for (int n = 0; n < 16; ++n) h[n] = 0.f;

    const float* __restrict__ rp = xdbl + (size_t)b * LSEQ * 45;   // uniform
    bf16* __restrict__ xp = xz + (size_t)b * LSEQ * 800 + d;

    // prologue: load t=0
    float cur[45];
#pragma unroll
    for (int j = 0; j < 45; ++j) cur[j] = rp[j];
    float ut = b2f(xp[0]);
    float zv = b2f(xp[400]);

#pragma unroll 2
    for (int t = 0; t < LSEQ; ++t) {
        // prefetch t+1 (independent of this step's compute)
        float nxt[45];
        float ut1 = 0.f, zv1 = 0.f;
        if (t + 1 < LSEQ) {
            const float* rn = rp + (size_t)(t + 1) * 45;
#pragma unroll
            for (int j = 0; j < 45; ++j) nxt[j] = rn[j];
            ut1 = b2f(xp[(size_t)(t + 1) * 800]);
            zv1 = b2f(xp[(size_t)(t + 1) * 800 + 400]);
        }
        // compute step t
        float dtv = bdt;
#pragma unroll
        for (int r = 0; r < 13; ++r) dtv += Wr[r] * cur[r];
        dtv = (dtv > 20.f) ? dtv : log1pf(expf(dtv));
        float du = dtv * ut;
        float yv = 0.f;
#pragma unroll
        for (int n = 0; n < 16; ++n) {
            float dA = expf(dtv * A[n]);
            h[n] = dA * h[n] + du * cur[13 + n];
            yv += h[n] * cur[29 + n];
        }
        yv += ut * Dv;
        float sig = 1.f / (1.f + expf(-zv));
        xp[(size_t)t * 800] = f2b(yv * zv * sig);
        // rotate
#pragma unroll
        for (int j = 0; j < 45; ++j) cur[j] = nxt[j];
        ut = ut1; zv = zv1;
    }
}

// ---------------- residual + layernorm over 200 ----------------
__global__ __launch_bounds__(256) void ln_res_kernel(const float* __restrict__ xa,
                                                     const float* __restrict__ xb,
                                                     const float* __restrict__ w,
                                                     const float* __restrict__ bias,
                                                     float* __restrict__ dst, int rows) {
    int wave = threadIdx.x >> 6;
    int lane = threadIdx.x & 63;
    int row = blockIdx.x * 4 + wave;
    if (row >= rows) return;
    const float* pa = xa + (size_t)row * DM;
    const float* pb = xb + (size_t)row * DM;
    float v[4];
    float sum = 0.f, sq = 0.f;
#pragma unroll
    for (int i = 0; i < 4; ++i) {
        int c = lane + i * 64;
        float t = 0.f;
        if (c < DM) t = pa[c] + pb[c];
        v[i] = t;
        sum += t;
        sq += t * t;
    }
#pragma unroll
    for (int off = 32; off > 0; off >>= 1) {
        sum += __shfl_down(sum, off);
        sq += __shfl_down(sq, off);
    }
    sum = __shfl(sum, 0);
    sq = __shfl(sq, 0);
    float mu = sum * (1.f / DM);
    float var = fmaxf(sq * (1.f / DM) - mu * mu, 0.f);
    float rstd = rsqrtf(var + 1e-12f);
    float* pd = dst + (size_t)row * DM;
#pragma unroll
    for (int i = 0; i < 4; ++i) {
        int c = lane + i * 64;
        if (c < DM) pd[c] = (v[i] - mu) * rstd * w[c] + bias[c];
    }
}

// ---------------- output split for a batch chunk (f32 out) ----------------
__global__ __launch_bounds__(256) void write_out_kernel(const float* __restrict__ h,
                                                        float* __restrict__ out,
                                                        int b0, int total /* rc*DM */) {
    int idx = blockIdx.x * 256 + threadIdx.x;
    if (idx >= total) return;
    int d = idx % DM;
    int bl = idx / DM;
    int l = bl % LSEQ;
    int b = b0 + bl / LSEQ;
    float v = h[idx];
    if (l == LSEQ - 1) {
        out[b * DM + d] = v;
    } else {
        out[(size_t)NB * DM + ((size_t)(b * (LSEQ - 1) + l) * DM + d)] = v;
    }
}

extern "C" void kernel_launch(void* const* d_in, const int* in_sizes, int n_in,
                              void* d_out, int out_size, void* d_ws, size_t ws_size,
                              hipStream_t stream) {
    fp emb       = (fp)d_in[0];
    fp in_proj_w = (fp)d_in[2];
    fp conv_w    = (fp)d_in[3];
    fp conv_b    = (fp)d_in[4];
    fp x_proj_w  = (fp)d_in[5];
    fp dt_proj_w = (fp)d_in[6];
    fp dt_proj_b = (fp)d_in[7];
    fp A_log     = (fp)d_in[8];
    fp Dw        = (fp)d_in[9];
    fp out_proj_w= (fp)d_in[10];
    fp ln1_w     = (fp)d_in[11];
    fp ln1_b     = (fp)d_in[12];
    fp ffn_w1    = (fp)d_in[13];
    fp ffn_b1    = (fp)d_in[14];
    fp ffn_w2    = (fp)d_in[15];
    fp ffn_b2    = (fp)d_in[16];
    fp ffn_ln_w  = (fp)d_in[17];
    fp ffn_ln_b  = (fp)d_in[18];

    // per-chunk bytes/row: xz 1600 + xdbl 180 + m 800 + h 800 = 3380; rc = cb*256
    const int cands[8] = {256, 128, 64, 32, 16, 8, 4, 2};
    int cb = 2;
    for (int ci = 0; ci < 8; ++ci) {
        size_t rcx = (size_t)cands[ci] * LSEQ;
        if (rcx * 3380 <= ws_size) { cb = cands[ci]; break; }
    }
    const size_t rc = (size_t)cb * LSEQ;

    bf16*  xz   = (bf16*)d_ws;                 // rc*800
    float* xdbl = (float*)(xz + rc * 800);     // rc*45
    float* m    = xdbl + rc * 45;              // rc*200
    float* h    = m + rc * 200;                // rc*200

    const int rcDM = (int)rc * DM;
    const int gm = (int)rc / 128;              // m-tiles

    for (int b0 = 0; b0 < NB; b0 += cb) {
        const float* emb_chunk = emb + (size_t)b0 * LSEQ * DM;

        for (int i = 0; i < 2; ++i) {
            fp w_in  = in_proj_w + (size_t)i * 800 * 200;
            fp cw    = conv_w + (size_t)i * 400 * 4;
            fp cbp   = conv_b + (size_t)i * 400;
            fp w_xp  = x_proj_w + (size_t)i * 45 * 400;
            fp w_dt  = dt_proj_w + (size_t)i * 400 * 13;
            fp b_dt  = dt_proj_b + (size_t)i * 400;
            fp Ai    = A_log + (size_t)i * 400 * 16;
            fp Di    = Dw + (size_t)i * 400;
            fp w_op  = out_proj_w + (size_t)i * 200 * 400;
            fp l1w   = ln1_w + (size_t)i * 200;
            fp l1b   = ln1_b + (size_t)i * 200;
            fp f1w   = ffn_w1 + (size_t)i * 800 * 200;
            fp f1b   = ffn_b1 + (size_t)i * 800;
            fp f2w   = ffn_w2 + (size_t)i * 200 * 800;
            fp f2b_  = ffn_b2 + (size_t)i * 200;
            fp flw   = ffn_ln_w + (size_t)i * 200;
            fp flb   = ffn_ln_b + (size_t)i * 200;

            const float* hin = (i == 0) ? emb_chunk : h;

            // xz = hin @ in_proj^T   (N=800, K=200)
            gemm_mfma<float, bf16, 0><<<dim3(gm, 7), 256, 0, stream>>>(
                hin, 200, w_in, nullptr, xz, 800, 800, 200);
            // conv + silu in-place on x-half
            conv_silu_inplace<<<(cb * DIE + 255) / 256, 256, 0, stream>>>(xz, cw, cbp, cb * DIE);
            // xdbl = xc @ x_proj^T   (N=45, K=400)
            gemm_mfma<bf16, float, 0><<<dim3(gm, 1), 256, 0, stream>>>(
                xz, 800, w_xp, nullptr, xdbl, 45, 45, 400);
            // fused scan; y in-place on x-half
            scan_kernel<<<cb * 2, 256, 0, stream>>>(xdbl, xz, w_dt, b_dt, Ai, Di);
            // m = y @ out_proj^T   (N=200, K=400)
            gemm_mfma<bf16, float, 0><<<dim3(gm, 2), 256, 0, stream>>>(
                xz, 800, w_op, nullptr, m, 200, 200, 400);
            // h = ln(m + hin)
            ln_res_kernel<<<rc / 4, 256, 0, stream>>>(m, hin, l1w, l1b, h, (int)rc);
            // f1 = gelu(h @ w1^T + b1) -> xz
            gemm_mfma<float, bf16, 2><<<dim3(gm, 7), 256, 0, stream>>>(
                h, 200, f1w, f1b, xz, 800, 800, 200);
            // f2 = f1 @ w2^T + b2 -> m   (N=200, K=800)
            gemm_mfma<bf16, float, 3><<<dim3(gm, 2), 256, 0, stream>>>(
                xz, 800, f2w, f2b_, m, 200, 200, 800);
            // h = ln(f2 + h)
            ln_res_kernel<<<rc / 4, 256, 0, stream>>>(m, h, flw, flb, h, (int)rc);
        }

        write_out_kernel<<<rcDM / 256, 256, 0, stream>>>(h, (float*)d_out, b0, rcDM);
    }
}